// Round 6
// baseline (288.445 us; speedup 1.0000x reference)
//
#include <hip/hip_runtime.h>
#include <math.h>

#define N_NODES 50000
#define N_EDGES 600000
#define D 128
#define TWO_D 256
#define BN_EPS 1e-5f
#define LN_EPS 1e-5f
#define ROW_BLOCKS 782   // ceil(50000/64)
#define LOG2E 1.44269504f

typedef __attribute__((ext_vector_type(8))) short short8;
typedef __attribute__((ext_vector_type(4))) float f32x4;

static __device__ __forceinline__ unsigned short f2b(float f) {
    unsigned int u = __builtin_bit_cast(unsigned int, f);
    u = u + 0x7fffu + ((u >> 16) & 1u);   // RNE
    return (unsigned short)(u >> 16);
}
static __device__ __forceinline__ float b2f(unsigned short s) {
    unsigned int u = ((unsigned int)s) << 16;
    return __builtin_bit_cast(float, u);
}
static __device__ __forceinline__ float lo_f(unsigned int p) {
    return __builtin_bit_cast(float, p << 16);
}
static __device__ __forceinline__ float hi_f(unsigned int p) {
    return __builtin_bit_cast(float, p & 0xffff0000u);
}

// ---------------- prep: x->bf16, W->bf16 transposed, zero bnacc, count+rank ----------------
// counts must be zeroed (memset) before this kernel.
__global__ __launch_bounds__(256) void prep_all(const float* __restrict__ x,
                                                const float* __restrict__ W1,
                                                const float* __restrict__ W2,
                                                const int* __restrict__ dst,
                                                unsigned short* __restrict__ W1t,
                                                unsigned short* __restrict__ W2t,
                                                unsigned int* __restrict__ xb2,
                                                int* __restrict__ counts,
                                                int* __restrict__ rank,
                                                float* __restrict__ bnacc) {
    int gid = blockIdx.x * 256 + threadIdx.x;       // grid 12500*256 = 3.2M = N*64 exact
    {
        float2 v = ((const float2*)x)[gid];
        xb2[gid] = (unsigned int)f2b(v.x) | ((unsigned int)f2b(v.y) << 16);
    }
    if (gid < 32768) {
        int n = gid >> 7, k = gid & 127;
        W1t[gid] = f2b(W1[k * 256 + n]);            // W1t[n][k] = W1[k][n]
    } else if (gid < 65536) {
        int j = gid - 32768;
        int n = j >> 8, k = j & 255;
        W2t[j] = f2b(W2[k * 128 + n]);              // W2t[n][k] = W2[k][n]
    }
    if (gid < 2 * TWO_D) bnacc[gid] = 0.f;
    if (gid < N_EDGES) rank[gid] = atomicAdd(&counts[dst[gid]], 1);
}

// ---------------- single-kernel exclusive scan: offsets[0..N] from counts ----------------
__global__ __launch_bounds__(256) void scan_offsets(const int* __restrict__ counts,
                                                    int* __restrict__ offsets) {
    __shared__ int buf[256];
    __shared__ int base_s;
    int tid = threadIdx.x;
    int start = blockIdx.x * 256;
    int part = 0;
    for (int j = tid; j < start; j += 256) part += counts[j];
    buf[tid] = part;
    __syncthreads();
    for (int off = 128; off > 0; off >>= 1) {
        if (tid < off) buf[tid] += buf[tid + off];
        __syncthreads();
    }
    if (tid == 0) base_s = buf[0];
    __syncthreads();
    int base = base_s;
    __syncthreads();
    int i = start + tid;
    int v = (i < N_NODES) ? counts[i] : 0;
    buf[tid] = v;
    __syncthreads();
    for (int off = 1; off < 256; off <<= 1) {
        int t = (tid >= off) ? buf[tid - off] : 0;
        __syncthreads();
        buf[tid] += t;
        __syncthreads();
    }
    if (i < N_NODES) offsets[i + 1] = base + buf[tid];
    if (i == 0) offsets[0] = 0;
}

// ---------------- scatter (atomic-free: rank precomputed) ----------------
__global__ void scatter_kernel(const int* __restrict__ src, const int* __restrict__ dst,
                               const int* __restrict__ offsets, const int* __restrict__ rank,
                               int* __restrict__ csr_src) {
    int i = blockIdx.x * blockDim.x + threadIdx.x;
    if (i < N_EDGES) csr_src[offsets[dst[i]] + rank[i]] = src[i];
}

// ---------------- softmax aggregation: 1 wave/node, SCALARIZED loop control ----------------
// node/beg/end/j in SGPRs via readfirstlane -> csr_src reads are s_load, loop is scalar-pipe.
__global__ __launch_bounds__(256) void agg_kernel(const unsigned int* __restrict__ xb2,
                                                  const int* __restrict__ offsets,
                                                  const int* __restrict__ csr_src,
                                                  const float* __restrict__ t_ptr,
                                                  unsigned int* __restrict__ h0b2) {
    int wq = __builtin_amdgcn_readfirstlane((int)(threadIdx.x >> 6));  // wave id, SGPR
    int node = blockIdx.x * 4 + wq;                   // SGPR
    int lane = threadIdx.x & 63;                      // 2 channels per lane
    int beg = offsets[node], end = offsets[node + 1]; // s_load
    float tl = t_ptr[0] * LOG2E;
    float s0 = 0.f, s1 = 0.f, m0 = 0.f, m1 = 0.f;
    float s0b = 0.f, s1b = 0.f, m0b = 0.f, m1b = 0.f;
    int j = beg;
    for (; j + 2 <= end; j += 2) {
        int sa = __builtin_amdgcn_readfirstlane(csr_src[j]);       // s_load
        int sb = __builtin_amdgcn_readfirstlane(csr_src[j + 1]);
        unsigned int pa = xb2[sa * 64 + lane];        // scalar-base + lane offset
        unsigned int pb = xb2[sb * 64 + lane];
        float ma0 = fmaxf(lo_f(pa), 0.f), ma1 = fmaxf(hi_f(pa), 0.f);
        float mc0 = fmaxf(lo_f(pb), 0.f), mc1 = fmaxf(hi_f(pb), 0.f);
        float ea0 = exp2f(ma0 * tl), ea1 = exp2f(ma1 * tl);
        float ec0 = exp2f(mc0 * tl), ec1 = exp2f(mc1 * tl);
        s0 += ea0; m0 = fmaf(ea0, ma0, m0);
        s1 += ea1; m1 = fmaf(ea1, ma1, m1);
        s0b += ec0; m0b = fmaf(ec0, mc0, m0b);
        s1b += ec1; m1b = fmaf(ec1, mc1, m1b);
    }
    if (j < end) {
        int sa = __builtin_amdgcn_readfirstlane(csr_src[j]);
        unsigned int pa = xb2[sa * 64 + lane];
        float ma0 = fmaxf(lo_f(pa), 0.f), ma1 = fmaxf(hi_f(pa), 0.f);
        float ea0 = exp2f(ma0 * tl), ea1 = exp2f(ma1 * tl);
        s0 += ea0; m0 = fmaf(ea0, ma0, m0);
        s1 += ea1; m1 = fmaf(ea1, ma1, m1);
    }
    float agg0 = (m0 + m0b) / (s0 + s0b + 1e-16f);
    float agg1 = (m1 + m1b) / (s1 + s1b + 1e-16f);
    unsigned int px = xb2[node * 64 + lane];          // bf16 residual
    h0b2[node * 64 + lane] = (unsigned int)f2b(agg0 + lo_f(px)) |
                             ((unsigned int)f2b(agg1 + hi_f(px)) << 16);
}

// ---------------- GEMM1 (MFMA), single pass over all 256 cols + fused BN partials ----------------
// grid 782; 4 waves stacked in M (64 rows); each wave: 16 rows x 256 cols (16 frags).
__global__ __launch_bounds__(256) void gemm1_mfma(const unsigned short* __restrict__ h0b,
                                                  const unsigned short* __restrict__ W1t,
                                                  const float* __restrict__ b1,
                                                  unsigned short* __restrict__ h1b,
                                                  float* __restrict__ partial_s,
                                                  float* __restrict__ partial_ss) {
    __shared__ float red_s[4][256];
    __shared__ float red_ss[4][256];
    int tid = threadIdx.x;
    int wave = tid >> 6, lane = tid & 63;
    int quad = lane >> 4, m16 = lane & 15;
    int row0 = blockIdx.x * 64 + wave * 16;

    f32x4 acc[16];
#pragma unroll
    for (int f = 0; f < 16; ++f) acc[f] = (f32x4){0.f, 0.f, 0.f, 0.f};

    int arow = row0 + m16;
    bool avalid = arow < N_NODES;
    const short8* aptr = (const short8*)(h0b + (avalid ? arow : 0) * D + quad * 8);
    short8 afr[4];
#pragma unroll
    for (int kk = 0; kk < 4; ++kk) {
        short8 a = aptr[kk * 4];
        if (!avalid) a = (short8)0;
        afr[kk] = a;
    }
#pragma unroll
    for (int kk = 0; kk < 4; ++kk) {
#pragma unroll
        for (int f = 0; f < 16; ++f) {
            const short8* bptr = (const short8*)(W1t + (f * 16 + m16) * D + quad * 8);
            acc[f] = __builtin_amdgcn_mfma_f32_16x16x32_bf16(afr[kk], bptr[kk * 4], acc[f], 0, 0, 0);
        }
    }
#pragma unroll
    for (int f = 0; f < 16; ++f) {
        int col = f * 16 + m16;
        float bias = b1[col];
        float ps = 0.f, pss = 0.f;
#pragma unroll
        for (int r = 0; r < 4; ++r) {
            int row = row0 + quad * 4 + r;
            float v = acc[f][r] + bias;
            if (row < N_NODES) {
                h1b[row * TWO_D + col] = f2b(v);
                ps += v;
                pss += v * v;
            }
        }
        ps  += __shfl_xor(ps, 16);  ps  += __shfl_xor(ps, 32);
        pss += __shfl_xor(pss, 16); pss += __shfl_xor(pss, 32);
        if (quad == 0) {
            red_s[wave][col] = ps;
            red_ss[wave][col] = pss;
        }
    }
    __syncthreads();
    if (tid < 256) {
        int base = blockIdx.x * 256 + tid;
        partial_s[base]  = red_s[0][tid] + red_s[1][tid] + red_s[2][tid] + red_s[3][tid];
        partial_ss[base] = red_ss[0][tid] + red_ss[1][tid] + red_ss[2][tid] + red_ss[3][tid];
    }
}

// ---------------- BN reduce partials -> bnacc (low-contention atomics) ----------------
__global__ __launch_bounds__(256) void bn_reduce(const float* __restrict__ partial_s,
                                                 const float* __restrict__ partial_ss,
                                                 float* __restrict__ bnacc) {
    int c = threadIdx.x;
    float s = 0.f, ss = 0.f;
    for (int rb = blockIdx.x; rb < ROW_BLOCKS; rb += 64) {
        s += partial_s[rb * 256 + c];
        ss += partial_ss[rb * 256 + c];
    }
    atomicAdd(&bnacc[c], s);
    atomicAdd(&bnacc[TWO_D + c], ss);
}

// ---------------- GEMM2 (MFMA): BN finalize in prologue, BN/ReLU staged, LN+mix+residual ----------------
__global__ __launch_bounds__(256) void gemm2_mfma(const unsigned short* __restrict__ h1b,
                                                  const float* __restrict__ bnacc,
                                                  const float* __restrict__ bn_g,
                                                  const float* __restrict__ bn_b,
                                                  const unsigned short* __restrict__ W2t,
                                                  const float* __restrict__ b2,
                                                  const float* __restrict__ ln_g,
                                                  const float* __restrict__ ln_b,
                                                  const unsigned int* __restrict__ xb2,
                                                  float* __restrict__ out) {
    __shared__ float sc_s[TWO_D], sh_s[TWO_D];
    __shared__ unsigned short As[16][264];
    __shared__ float yt[16][132];
    __shared__ float mu_s[16], rstd_s[16];
    int tid = threadIdx.x;
    {   // BN finalize per block (bnacc is L2-resident, 2KB)
        float mean = bnacc[tid] * (1.f / N_NODES);
        float var = bnacc[TWO_D + tid] * (1.f / N_NODES) - mean * mean;
        float sc = bn_g[tid] * rsqrtf(var + BN_EPS);
        sc_s[tid] = sc;
        sh_s[tid] = bn_b[tid] - mean * sc;
    }
    __syncthreads();

    int row0 = blockIdx.x * 16;                       // 50000/16 = 3125 exact
    {
        int r = tid >> 4, c0 = (tid & 15) * 16;
        const unsigned short* srcp = h1b + (row0 + r) * TWO_D + c0;
        short8 v0 = *(const short8*)(srcp);
        short8 v1 = *(const short8*)(srcp + 8);
        short8 o0, o1;
#pragma unroll
        for (int jj = 0; jj < 8; ++jj) {
            float v = b2f((unsigned short)v0[jj]);
            v = fmaxf(v * sc_s[c0 + jj] + sh_s[c0 + jj], 0.f);
            o0[jj] = (short)f2b(v);
            float w = b2f((unsigned short)v1[jj]);
            w = fmaxf(w * sc_s[c0 + 8 + jj] + sh_s[c0 + 8 + jj], 0.f);
            o1[jj] = (short)f2b(w);
        }
        *(short8*)&As[r][c0] = o0;
        *(short8*)&As[r][c0 + 8] = o1;
    }
    __syncthreads();

    int wave = tid >> 6, lane = tid & 63;
    int quad = lane >> 4, m16 = lane & 15;
    f32x4 acc[2] = {{0.f,0.f,0.f,0.f},{0.f,0.f,0.f,0.f}};
#pragma unroll
    for (int kk = 0; kk < 8; ++kk) {
        short8 a = *(const short8*)&As[m16][kk * 32 + quad * 8];
#pragma unroll
        for (int f = 0; f < 2; ++f) {
            const short8* bptr = (const short8*)(W2t + (wave * 32 + f * 16 + m16) * TWO_D + kk * 32 + quad * 8);
            acc[f] = __builtin_amdgcn_mfma_f32_16x16x32_bf16(a, *bptr, acc[f], 0, 0, 0);
        }
    }
#pragma unroll
    for (int f = 0; f < 2; ++f) {
        int col = wave * 32 + f * 16 + m16;
        float bias = b2[col];
#pragma unroll
        for (int r = 0; r < 4; ++r) yt[quad * 4 + r][col] = acc[f][r] + bias;
    }
    __syncthreads();
    {   // LN stats: 16 threads per row
        int r = tid >> 4, lane16 = tid & 15;
        float s = 0.f, ss = 0.f;
        for (int jj = lane16; jj < D; jj += 16) {
            float v = yt[r][jj];
            s += v;
            ss += v * v;
        }
#pragma unroll
        for (int o = 1; o < 16; o <<= 1) {
            s += __shfl_xor(s, o);
            ss += __shfl_xor(ss, o);
        }
        if (lane16 == 0) {
            float mu = s * (1.f / D);
            float var = ss * (1.f / D) - mu * mu;
            mu_s[r] = mu;
            rstd_s[r] = rsqrtf(var + LN_EPS);
        }
    }
    __syncthreads();
    // epilogue: 2 channels/thread, bf16 residual, float2 stores
    int cp = tid & 63, rg = tid >> 6;                 // channel pair, row group
    float lg0 = ln_g[2 * cp], lg1 = ln_g[2 * cp + 1];
    float lb0 = ln_b[2 * cp], lb1 = ln_b[2 * cp + 1];
#pragma unroll
    for (int rp = 0; rp < 4; ++rp) {
        int rl = rp * 4 + rg;
        int row = row0 + rl;
        unsigned int px = xb2[row * 64 + cp];
        float z0 = (yt[rl][2 * cp] - mu_s[rl]) * rstd_s[rl] * lg0 + lb0;
        float z1 = (yt[rl][2 * cp + 1] - mu_s[rl]) * rstd_s[rl] * lg1 + lb1;
        float o0 = 0.5f * lo_f(px) + 0.5f * fmaxf(z0, 0.f) + 0.5f * z0;
        float o1 = 0.5f * hi_f(px) + 0.5f * fmaxf(z1, 0.f) + 0.5f * z1;
        ((float2*)out)[row * 64 + cp] = make_float2(o0, o1);
    }
}

// ---------------- launch ----------------

extern "C" void kernel_launch(void* const* d_in, const int* in_sizes, int n_in,
                              void* d_out, int out_size, void* d_ws, size_t ws_size,
                              hipStream_t stream) {
    const float* x    = (const float*)d_in[0];
    const int*   ei   = (const int*)d_in[1];
    const float* t    = (const float*)d_in[2];
    const float* W1   = (const float*)d_in[3];
    const float* b1   = (const float*)d_in[4];
    const float* bn_g = (const float*)d_in[5];
    const float* bn_b = (const float*)d_in[6];
    const float* W2   = (const float*)d_in[7];
    const float* b2   = (const float*)d_in[8];
    const float* ln_g = (const float*)d_in[9];
    const float* ln_b = (const float*)d_in[10];
    float* out = (float*)d_out;

    char* ws = (char*)d_ws;
    size_t off = 0;
    auto alloc = [&](size_t bytes) -> void* {
        void* p = ws + off;
        off = (off + bytes + 255) & ~(size_t)255;
        return p;
    };
    int*            counts     = (int*)alloc((size_t)N_NODES * 4);
    int*            offsets    = (int*)alloc((size_t)(N_NODES + 1) * 4);
    int*            rank       = (int*)alloc((size_t)N_EDGES * 4);
    int*            csr_src    = (int*)alloc((size_t)N_EDGES * 4);
    unsigned int*   xb2        = (unsigned int*)alloc((size_t)N_NODES * 64 * 4);
    unsigned int*   h0b2       = (unsigned int*)alloc((size_t)N_NODES * 64 * 4);
    unsigned short* h1b        = (unsigned short*)alloc((size_t)N_NODES * TWO_D * 2);
    unsigned short* W1t        = (unsigned short*)alloc((size_t)D * TWO_D * 2);
    unsigned short* W2t        = (unsigned short*)alloc((size_t)D * TWO_D * 2);
    float*          partial_s  = (float*)alloc((size_t)ROW_BLOCKS * TWO_D * 4);
    float*          partial_ss = (float*)alloc((size_t)ROW_BLOCKS * TWO_D * 4);
    float*          bnacc      = (float*)alloc(2 * TWO_D * 4);

    const int* src = ei;
    const int* dst = ei + N_EDGES;

    hipMemsetAsync(counts, 0, (size_t)N_NODES * 4, stream);
    prep_all<<<12500, 256, 0, stream>>>(x, W1, W2, dst, W1t, W2t, xb2, counts, rank, bnacc);
    scan_offsets<<<196, 256, 0, stream>>>(counts, offsets);
    scatter_kernel<<<(N_EDGES + 255) / 256, 256, 0, stream>>>(src, dst, offsets, rank, csr_src);
    agg_kernel<<<12500, 256, 0, stream>>>(xb2, offsets, csr_src, t, h0b2);
    gemm1_mfma<<<ROW_BLOCKS, 256, 0, stream>>>((const unsigned short*)h0b2, W1t, b1, h1b,
                                               partial_s, partial_ss);
    bn_reduce<<<64, 256, 0, stream>>>(partial_s, partial_ss, bnacc);
    gemm2_mfma<<<N_NODES / 16, 256, 0, stream>>>(h1b, bnacc, bn_g, bn_b, W2t, b2,
                                                 ln_g, ln_b, xb2, out);
}

// Round 7
// 238.548 us; speedup vs baseline: 1.2092x; 1.2092x over previous
//
#include <hip/hip_runtime.h>
#include <math.h>

#define N_NODES 50000
#define N_EDGES 600000
#define D 128
#define TWO_D 256
#define BN_EPS 1e-5f
#define LN_EPS 1e-5f
#define LOG2E 1.44269504f
#define GRID_G 391      // GEMM grid: 391 blocks x 8 tiles = 3128 >= 3125
#define TILES 3125      // 50000 / 16 exact

typedef __attribute__((ext_vector_type(8))) short short8;
typedef __attribute__((ext_vector_type(4))) float f32x4;

static __device__ __forceinline__ unsigned short f2b(float f) {
    unsigned int u = __builtin_bit_cast(unsigned int, f);
    u = u + 0x7fffu + ((u >> 16) & 1u);   // RNE
    return (unsigned short)(u >> 16);
}
static __device__ __forceinline__ float b2f(unsigned short s) {
    unsigned int u = ((unsigned int)s) << 16;
    return __builtin_bit_cast(float, u);
}
static __device__ __forceinline__ float lo_f(unsigned int p) {
    return __builtin_bit_cast(float, p << 16);
}
static __device__ __forceinline__ float hi_f(unsigned int p) {
    return __builtin_bit_cast(float, p & 0xffff0000u);
}

// ---------------- prep: x->bf16, W->bf16 transposed, zero bnacc, count+rank ----------------
// counts must be zeroed (memset) before this kernel.
__global__ __launch_bounds__(256) void prep_all(const float* __restrict__ x,
                                                const float* __restrict__ W1,
                                                const float* __restrict__ W2,
                                                const int* __restrict__ dst,
                                                unsigned short* __restrict__ W1t,
                                                unsigned short* __restrict__ W2t,
                                                unsigned int* __restrict__ xb2,
                                                int* __restrict__ counts,
                                                int* __restrict__ rank,
                                                float* __restrict__ bnacc) {
    int gid = blockIdx.x * 256 + threadIdx.x;       // grid 12500*256 = 3.2M = N*64 exact
    {
        float2 v = ((const float2*)x)[gid];
        xb2[gid] = (unsigned int)f2b(v.x) | ((unsigned int)f2b(v.y) << 16);
    }
    if (gid < 32768) {
        int n = gid >> 7, k = gid & 127;
        W1t[gid] = f2b(W1[k * 256 + n]);            // W1t[n][k] = W1[k][n]
    } else if (gid < 65536) {
        int j = gid - 32768;
        int n = j >> 8, k = j & 255;
        W2t[j] = f2b(W2[k * 128 + n]);              // W2t[n][k] = W2[k][n]
    }
    if (gid < 2 * TWO_D) bnacc[gid] = 0.f;
    if (gid < N_EDGES) rank[gid] = atomicAdd(&counts[dst[gid]], 1);
}

// ---------------- single-kernel exclusive scan: offsets[0..N] from counts ----------------
__global__ __launch_bounds__(256) void scan_offsets(const int* __restrict__ counts,
                                                    int* __restrict__ offsets) {
    __shared__ int buf[256];
    __shared__ int base_s;
    int tid = threadIdx.x;
    int start = blockIdx.x * 256;
    int part = 0;
    for (int j = tid; j < start; j += 256) part += counts[j];
    buf[tid] = part;
    __syncthreads();
    for (int off = 128; off > 0; off >>= 1) {
        if (tid < off) buf[tid] += buf[tid + off];
        __syncthreads();
    }
    if (tid == 0) base_s = buf[0];
    __syncthreads();
    int base = base_s;
    __syncthreads();
    int i = start + tid;
    int v = (i < N_NODES) ? counts[i] : 0;
    buf[tid] = v;
    __syncthreads();
    for (int off = 1; off < 256; off <<= 1) {
        int t = (tid >= off) ? buf[tid - off] : 0;
        __syncthreads();
        buf[tid] += t;
        __syncthreads();
    }
    if (i < N_NODES) offsets[i + 1] = base + buf[tid];
    if (i == 0) offsets[0] = 0;
}

// ---------------- scatter (atomic-free: rank precomputed) ----------------
__global__ void scatter_kernel(const int* __restrict__ src, const int* __restrict__ dst,
                               const int* __restrict__ offsets, const int* __restrict__ rank,
                               int* __restrict__ csr_src) {
    int i = blockIdx.x * blockDim.x + threadIdx.x;
    if (i < N_EDGES) csr_src[offsets[dst[i]] + rank[i]] = src[i];
}

// ---------------- softmax aggregation: 1 wave/node, scalarized loop control ----------------
__global__ __launch_bounds__(256) void agg_kernel(const unsigned int* __restrict__ xb2,
                                                  const int* __restrict__ offsets,
                                                  const int* __restrict__ csr_src,
                                                  const float* __restrict__ t_ptr,
                                                  unsigned int* __restrict__ h0b2) {
    int wq = __builtin_amdgcn_readfirstlane((int)(threadIdx.x >> 6));  // wave id, SGPR
    int node = blockIdx.x * 4 + wq;                   // SGPR
    int lane = threadIdx.x & 63;                      // 2 channels per lane
    int beg = offsets[node], end = offsets[node + 1]; // s_load
    float tl = t_ptr[0] * LOG2E;
    float s0 = 0.f, s1 = 0.f, m0 = 0.f, m1 = 0.f;
    float s0b = 0.f, s1b = 0.f, m0b = 0.f, m1b = 0.f;
    int j = beg;
    for (; j + 2 <= end; j += 2) {
        int sa = __builtin_amdgcn_readfirstlane(csr_src[j]);       // s_load
        int sb = __builtin_amdgcn_readfirstlane(csr_src[j + 1]);
        unsigned int pa = xb2[sa * 64 + lane];        // scalar-base + lane offset
        unsigned int pb = xb2[sb * 64 + lane];
        float ma0 = fmaxf(lo_f(pa), 0.f), ma1 = fmaxf(hi_f(pa), 0.f);
        float mc0 = fmaxf(lo_f(pb), 0.f), mc1 = fmaxf(hi_f(pb), 0.f);
        float ea0 = exp2f(ma0 * tl), ea1 = exp2f(ma1 * tl);
        float ec0 = exp2f(mc0 * tl), ec1 = exp2f(mc1 * tl);
        s0 += ea0; m0 = fmaf(ea0, ma0, m0);
        s1 += ea1; m1 = fmaf(ea1, ma1, m1);
        s0b += ec0; m0b = fmaf(ec0, mc0, m0b);
        s1b += ec1; m1b = fmaf(ec1, mc1, m1b);
    }
    if (j < end) {
        int sa = __builtin_amdgcn_readfirstlane(csr_src[j]);
        unsigned int pa = xb2[sa * 64 + lane];
        float ma0 = fmaxf(lo_f(pa), 0.f), ma1 = fmaxf(hi_f(pa), 0.f);
        float ea0 = exp2f(ma0 * tl), ea1 = exp2f(ma1 * tl);
        s0 += ea0; m0 = fmaf(ea0, ma0, m0);
        s1 += ea1; m1 = fmaf(ea1, ma1, m1);
    }
    float agg0 = (m0 + m0b) / (s0 + s0b + 1e-16f);
    float agg1 = (m1 + m1b) / (s1 + s1b + 1e-16f);
    unsigned int px = xb2[node * 64 + lane];          // bf16 residual
    h0b2[node * 64 + lane] = (unsigned int)f2b(agg0 + lo_f(px)) |
                             ((unsigned int)f2b(agg1 + hi_f(px)) << 16);
}

// ---------------- GEMM1 (MFMA): persistent B in registers, M-loop ----------------
// 391 blocks x 4 waves; wave w owns cols w*64..w*64+63 (B = 16 short8 regs, loaded once).
// Loop over 16-row tiles: 4 A-loads -> 16 MFMAs -> bias+store + BN partial accumulation.
__global__ __launch_bounds__(256) void gemm1_mfma(const unsigned short* __restrict__ h0b,
                                                  const unsigned short* __restrict__ W1t,
                                                  const float* __restrict__ b1,
                                                  unsigned short* __restrict__ h1b,
                                                  float* __restrict__ partial_s,
                                                  float* __restrict__ partial_ss) {
    __shared__ float red_s[4][256];
    __shared__ float red_ss[4][256];
    int tid = threadIdx.x;
    int wave = tid >> 6, lane = tid & 63;
    int quad = lane >> 4, m16 = lane & 15;
    int col0 = wave * 64;

    short8 bfr[4][4];    // [kk][f] resident weight fragments
    float bias[4];
#pragma unroll
    for (int f = 0; f < 4; ++f) {
        bias[f] = b1[col0 + f * 16 + m16];
#pragma unroll
        for (int kk = 0; kk < 4; ++kk)
            bfr[kk][f] = *(const short8*)(W1t + (col0 + f * 16 + m16) * D + kk * 32 + quad * 8);
    }
    float ps[4] = {0.f, 0.f, 0.f, 0.f}, pss[4] = {0.f, 0.f, 0.f, 0.f};

    for (int it = blockIdx.x; it < TILES; it += GRID_G) {
        int row0 = it * 16;                            // rows always < 50000 (3125*16 exact)
        const short8* aptr = (const short8*)(h0b + (row0 + m16) * D + quad * 8);
        short8 afr[4];
#pragma unroll
        for (int kk = 0; kk < 4; ++kk) afr[kk] = aptr[kk * 4];
        f32x4 acc[4];
#pragma unroll
        for (int f = 0; f < 4; ++f) acc[f] = (f32x4){0.f, 0.f, 0.f, 0.f};
#pragma unroll
        for (int kk = 0; kk < 4; ++kk)
#pragma unroll
            for (int f = 0; f < 4; ++f)
                acc[f] = __builtin_amdgcn_mfma_f32_16x16x32_bf16(afr[kk], bfr[kk][f], acc[f], 0, 0, 0);
#pragma unroll
        for (int f = 0; f < 4; ++f) {
            int col = col0 + f * 16 + m16;
#pragma unroll
            for (int r = 0; r < 4; ++r) {
                float v = acc[f][r] + bias[f];
                h1b[(row0 + quad * 4 + r) * TWO_D + col] = f2b(v);
                ps[f] += v;
                pss[f] += v * v;
            }
        }
    }
    // reduce BN partials: combine quads, then waves via LDS; one write per column
#pragma unroll
    for (int f = 0; f < 4; ++f) {
        float s = ps[f], ss = pss[f];
        s += __shfl_xor(s, 16);  s += __shfl_xor(s, 32);
        ss += __shfl_xor(ss, 16); ss += __shfl_xor(ss, 32);
        if (quad == 0) {
            red_s[wave][col0 + f * 16 + m16] = s;
            red_ss[wave][col0 + f * 16 + m16] = ss;
        }
    }
    __syncthreads();
    {
        int base = blockIdx.x * 256 + tid;
        partial_s[base]  = red_s[0][tid] + red_s[1][tid] + red_s[2][tid] + red_s[3][tid];
        partial_ss[base] = red_ss[0][tid] + red_ss[1][tid] + red_ss[2][tid] + red_ss[3][tid];
    }
}

// ---------------- BN reduce partials -> bnacc (low-contention atomics) ----------------
__global__ __launch_bounds__(256) void bn_reduce(const float* __restrict__ partial_s,
                                                 const float* __restrict__ partial_ss,
                                                 float* __restrict__ bnacc) {
    int c = threadIdx.x;
    float s = 0.f, ss = 0.f;
    for (int rb = blockIdx.x; rb < GRID_G; rb += 64) {
        s += partial_s[rb * 256 + c];
        ss += partial_ss[rb * 256 + c];
    }
    atomicAdd(&bnacc[c], s);
    atomicAdd(&bnacc[TWO_D + c], ss);
}

// ---------------- GEMM2 (MFMA): persistent B, M-loop; BN finalize + BN/ReLU stage + LN + mix ----------------
// 391 blocks x 4 waves; wave w owns cols w*32..+31 (B = 16 short8 regs). Per 16-row tile:
// stage BN/ReLU'd A in LDS -> 16 MFMAs -> LN in-block -> epilogue.
__global__ __launch_bounds__(256) void gemm2_mfma(const unsigned short* __restrict__ h1b,
                                                  const float* __restrict__ bnacc,
                                                  const float* __restrict__ bn_g,
                                                  const float* __restrict__ bn_b,
                                                  const unsigned short* __restrict__ W2t,
                                                  const float* __restrict__ b2,
                                                  const float* __restrict__ ln_g,
                                                  const float* __restrict__ ln_b,
                                                  const unsigned int* __restrict__ xb2,
                                                  float* __restrict__ out) {
    __shared__ float sc_s[TWO_D], sh_s[TWO_D];
    __shared__ unsigned short As[16][264];
    __shared__ float yt[16][132];
    __shared__ float mu_s[16], rstd_s[16];
    int tid = threadIdx.x;
    int wave = tid >> 6, lane = tid & 63;
    int quad = lane >> 4, m16 = lane & 15;

    {   // BN finalize per block (bnacc is 2KB, L2-resident)
        float mean = bnacc[tid] * (1.f / N_NODES);
        float var = bnacc[TWO_D + tid] * (1.f / N_NODES) - mean * mean;
        float sc = bn_g[tid] * rsqrtf(var + BN_EPS);
        sc_s[tid] = sc;
        sh_s[tid] = bn_b[tid] - mean * sc;
    }
    short8 bfr[8][2];    // resident W2t fragments: wave cols wave*32 + f*16 + m16
    float bias[2];
#pragma unroll
    for (int f = 0; f < 2; ++f) {
        int col = wave * 32 + f * 16 + m16;
        bias[f] = b2[col];
#pragma unroll
        for (int kk = 0; kk < 8; ++kk)
            bfr[kk][f] = *(const short8*)(W2t + col * TWO_D + kk * 32 + quad * 8);
    }
    int cp = tid & 63, rg = tid >> 6;                 // epilogue: channel pair / row group
    float lg0 = ln_g[2 * cp], lg1 = ln_g[2 * cp + 1];
    float lb0 = ln_b[2 * cp], lb1 = ln_b[2 * cp + 1];
    int sr = tid >> 4, sc0 = (tid & 15) * 16;         // staging coords
    __syncthreads();

    for (int it = blockIdx.x; it < TILES; it += GRID_G) {
        int row0 = it * 16;
        {   // stage BN+ReLU'd A tile
            const unsigned short* srcp = h1b + (row0 + sr) * TWO_D + sc0;
            short8 v0 = *(const short8*)(srcp);
            short8 v1 = *(const short8*)(srcp + 8);
            short8 o0, o1;
#pragma unroll
            for (int jj = 0; jj < 8; ++jj) {
                float v = b2f((unsigned short)v0[jj]);
                v = fmaxf(v * sc_s[sc0 + jj] + sh_s[sc0 + jj], 0.f);
                o0[jj] = (short)f2b(v);
                float w = b2f((unsigned short)v1[jj]);
                w = fmaxf(w * sc_s[sc0 + 8 + jj] + sh_s[sc0 + 8 + jj], 0.f);
                o1[jj] = (short)f2b(w);
            }
            *(short8*)&As[sr][sc0] = o0;
            *(short8*)&As[sr][sc0 + 8] = o1;
        }
        __syncthreads();
        f32x4 acc[2] = {{0.f,0.f,0.f,0.f},{0.f,0.f,0.f,0.f}};
#pragma unroll
        for (int kk = 0; kk < 8; ++kk) {
            short8 a = *(const short8*)&As[m16][kk * 32 + quad * 8];
#pragma unroll
            for (int f = 0; f < 2; ++f)
                acc[f] = __builtin_amdgcn_mfma_f32_16x16x32_bf16(a, bfr[kk][f], acc[f], 0, 0, 0);
        }
#pragma unroll
        for (int f = 0; f < 2; ++f) {
            int col = wave * 32 + f * 16 + m16;
#pragma unroll
            for (int r = 0; r < 4; ++r) yt[quad * 4 + r][col] = acc[f][r] + bias[f];
        }
        __syncthreads();
        {   // LN stats: 16 threads per row
            int r = tid >> 4, lane16 = tid & 15;
            float s = 0.f, ss = 0.f;
            for (int jj = lane16; jj < D; jj += 16) {
                float v = yt[r][jj];
                s += v;
                ss += v * v;
            }
#pragma unroll
            for (int o = 1; o < 16; o <<= 1) {
                s += __shfl_xor(s, o);
                ss += __shfl_xor(ss, o);
            }
            if (lane16 == 0) {
                float mu = s * (1.f / D);
                float var = ss * (1.f / D) - mu * mu;
                mu_s[r] = mu;
                rstd_s[r] = rsqrtf(var + LN_EPS);
            }
        }
        __syncthreads();
        // epilogue: 2 channels/thread, bf16 residual, float2 stores
#pragma unroll
        for (int rp = 0; rp < 4; ++rp) {
            int rl = rp * 4 + rg;
            int row = row0 + rl;
            unsigned int px = xb2[row * 64 + cp];
            float z0 = (yt[rl][2 * cp] - mu_s[rl]) * rstd_s[rl] * lg0 + lb0;
            float z1 = (yt[rl][2 * cp + 1] - mu_s[rl]) * rstd_s[rl] * lg1 + lb1;
            float o0 = 0.5f * lo_f(px) + 0.5f * fmaxf(z0, 0.f) + 0.5f * z0;
            float o1 = 0.5f * hi_f(px) + 0.5f * fmaxf(z1, 0.f) + 0.5f * z1;
            ((float2*)out)[row * 64 + cp] = make_float2(o0, o1);
        }
        // no trailing barrier needed: all As/yt reads of this tile complete before
        // the next tile's post-staging barrier can be crossed.
    }
}

// ---------------- launch ----------------

extern "C" void kernel_launch(void* const* d_in, const int* in_sizes, int n_in,
                              void* d_out, int out_size, void* d_ws, size_t ws_size,
                              hipStream_t stream) {
    const float* x    = (const float*)d_in[0];
    const int*   ei   = (const int*)d_in[1];
    const float* t    = (const float*)d_in[2];
    const float* W1   = (const float*)d_in[3];
    const float* b1   = (const float*)d_in[4];
    const float* bn_g = (const float*)d_in[5];
    const float* bn_b = (const float*)d_in[6];
    const float* W2   = (const float*)d_in[7];
    const float* b2   = (const float*)d_in[8];
    const float* ln_g = (const float*)d_in[9];
    const float* ln_b = (const float*)d_in[10];
    float* out = (float*)d_out;

    char* ws = (char*)d_ws;
    size_t off = 0;
    auto alloc = [&](size_t bytes) -> void* {
        void* p = ws + off;
        off = (off + bytes + 255) & ~(size_t)255;
        return p;
    };
    int*            counts     = (int*)alloc((size_t)N_NODES * 4);
    int*            offsets    = (int*)alloc((size_t)(N_NODES + 1) * 4);
    int*            rank       = (int*)alloc((size_t)N_EDGES * 4);
    int*            csr_src    = (int*)alloc((size_t)N_EDGES * 4);
    unsigned int*   xb2        = (unsigned int*)alloc((size_t)N_NODES * 64 * 4);
    unsigned int*   h0b2       = (unsigned int*)alloc((size_t)N_NODES * 64 * 4);
    unsigned short* h1b        = (unsigned short*)alloc((size_t)N_NODES * TWO_D * 2);
    unsigned short* W1t        = (unsigned short*)alloc((size_t)D * TWO_D * 2);
    unsigned short* W2t        = (unsigned short*)alloc((size_t)D * TWO_D * 2);
    float*          partial_s  = (float*)alloc((size_t)GRID_G * TWO_D * 4);
    float*          partial_ss = (float*)alloc((size_t)GRID_G * TWO_D * 4);
    float*          bnacc      = (float*)alloc(2 * TWO_D * 4);

    const int* src = ei;
    const int* dst = ei + N_EDGES;

    hipMemsetAsync(counts, 0, (size_t)N_NODES * 4, stream);
    prep_all<<<12500, 256, 0, stream>>>(x, W1, W2, dst, W1t, W2t, xb2, counts, rank, bnacc);
    scan_offsets<<<196, 256, 0, stream>>>(counts, offsets);
    scatter_kernel<<<(N_EDGES + 255) / 256, 256, 0, stream>>>(src, dst, offsets, rank, csr_src);
    agg_kernel<<<12500, 256, 0, stream>>>(xb2, offsets, csr_src, t, h0b2);
    gemm1_mfma<<<GRID_G, 256, 0, stream>>>((const unsigned short*)h0b2, W1t, b1, h1b,
                                           partial_s, partial_ss);
    bn_reduce<<<64, 256, 0, stream>>>(partial_s, partial_ss, bnacc);
    gemm2_mfma<<<GRID_G, 256, 0, stream>>>(h1b, bnacc, bn_g, bn_b, W2t, b2,
                                           ln_g, ln_b, xb2, out);
}

// Round 9
// 237.428 us; speedup vs baseline: 1.2149x; 1.0047x over previous
//
#include <hip/hip_runtime.h>
#include <math.h>

#define N_NODES 50000
#define N_EDGES 600000
#define D 128
#define TWO_D 256
#define BN_EPS 1e-5f
#define LN_EPS 1e-5f
#define LOG2E 1.44269504f
#define GRID_G 391      // GEMM grid: 391 blocks x 8 tiles = 3128 >= 3125
#define TILES 3125      // 50000 / 16 exact

typedef __attribute__((ext_vector_type(8))) short short8;
typedef __attribute__((ext_vector_type(4))) float f32x4;

static __device__ __forceinline__ unsigned short f2b(float f) {
    unsigned int u = __builtin_bit_cast(unsigned int, f);
    u = u + 0x7fffu + ((u >> 16) & 1u);   // RNE
    return (unsigned short)(u >> 16);
}
static __device__ __forceinline__ float b2f(unsigned short s) {
    unsigned int u = ((unsigned int)s) << 16;
    return __builtin_bit_cast(float, u);
}
static __device__ __forceinline__ float lo_f(unsigned int p) {
    return __builtin_bit_cast(float, p << 16);
}
static __device__ __forceinline__ float hi_f(unsigned int p) {
    return __builtin_bit_cast(float, p & 0xffff0000u);
}

// ---------------- prep: x->bf16, W->bf16 transposed, zero bnacc, count+rank ----------------
// counts must be zeroed (memset) before this kernel.
__global__ __launch_bounds__(256) void prep_all(const float* __restrict__ x,
                                                const float* __restrict__ W1,
                                                const float* __restrict__ W2,
                                                const int* __restrict__ dst,
                                                unsigned short* __restrict__ W1t,
                                                unsigned short* __restrict__ W2t,
                                                unsigned int* __restrict__ xb2,
                                                int* __restrict__ counts,
                                                int* __restrict__ rank,
                                                float* __restrict__ bnacc) {
    int gid = blockIdx.x * 256 + threadIdx.x;       // grid 12500*256 = 3.2M = N*64 exact
    {
        float2 v = ((const float2*)x)[gid];
        xb2[gid] = (unsigned int)f2b(v.x) | ((unsigned int)f2b(v.y) << 16);
    }
    if (gid < 32768) {
        int n = gid >> 7, k = gid & 127;
        W1t[gid] = f2b(W1[k * 256 + n]);            // W1t[n][k] = W1[k][n]
    } else if (gid < 65536) {
        int j = gid - 32768;
        int n = j >> 8, k = j & 255;
        W2t[j] = f2b(W2[k * 128 + n]);              // W2t[n][k] = W2[k][n]
    }
    if (gid < 2 * TWO_D) bnacc[gid] = 0.f;
    if (gid < N_EDGES) rank[gid] = atomicAdd(&counts[dst[gid]], 1);
}

// ---------------- single-kernel exclusive scan: offsets[0..N] from counts ----------------
__global__ __launch_bounds__(256) void scan_offsets(const int* __restrict__ counts,
                                                    int* __restrict__ offsets) {
    __shared__ int buf[256];
    __shared__ int base_s;
    int tid = threadIdx.x;
    int start = blockIdx.x * 256;
    int part = 0;
    for (int j = tid; j < start; j += 256) part += counts[j];
    buf[tid] = part;
    __syncthreads();
    for (int off = 128; off > 0; off >>= 1) {
        if (tid < off) buf[tid] += buf[tid + off];
        __syncthreads();
    }
    if (tid == 0) base_s = buf[0];
    __syncthreads();
    int base = base_s;
    __syncthreads();
    int i = start + tid;
    int v = (i < N_NODES) ? counts[i] : 0;
    buf[tid] = v;
    __syncthreads();
    for (int off = 1; off < 256; off <<= 1) {
        int t = (tid >= off) ? buf[tid - off] : 0;
        __syncthreads();
        buf[tid] += t;
        __syncthreads();
    }
    if (i < N_NODES) offsets[i + 1] = base + buf[tid];
    if (i == 0) offsets[0] = 0;
}

// ---------------- scatter (atomic-free: rank precomputed) ----------------
__global__ void scatter_kernel(const int* __restrict__ src, const int* __restrict__ dst,
                               const int* __restrict__ offsets, const int* __restrict__ rank,
                               int* __restrict__ csr_src) {
    int i = blockIdx.x * blockDim.x + threadIdx.x;
    if (i < N_EDGES) csr_src[offsets[dst[i]] + rank[i]] = src[i];
}

// ---------------- softmax aggregation: 1 wave/node, scalar index feed, unroll-4 ----------------
// j is wave-uniform -> csr_src[j] compiles to s_load (proven in R7). Four independent
// s_loads + four independent 256B gathers in flight per iteration.
__global__ __launch_bounds__(256) void agg_kernel(const unsigned int* __restrict__ xb2,
                                                  const int* __restrict__ offsets,
                                                  const int* __restrict__ csr_src,
                                                  const float* __restrict__ t_ptr,
                                                  unsigned int* __restrict__ h0b2) {
    int wq = __builtin_amdgcn_readfirstlane((int)(threadIdx.x >> 6));  // wave id, SGPR
    int node = blockIdx.x * 4 + wq;                   // SGPR
    int lane = threadIdx.x & 63;                      // 2 channels per lane
    int beg = offsets[node], end = offsets[node + 1]; // s_load
    float tl = t_ptr[0] * LOG2E;
    float s0 = 0.f, s1 = 0.f, m0 = 0.f, m1 = 0.f;
    float s0b = 0.f, s1b = 0.f, m0b = 0.f, m1b = 0.f;
    int j = beg;
    for (; j + 4 <= end; j += 4) {
        int sa = __builtin_amdgcn_readfirstlane(csr_src[j]);       // 4 independent s_loads
        int sb = __builtin_amdgcn_readfirstlane(csr_src[j + 1]);
        int sc = __builtin_amdgcn_readfirstlane(csr_src[j + 2]);
        int sd = __builtin_amdgcn_readfirstlane(csr_src[j + 3]);
        unsigned int pa = xb2[sa * 64 + lane];        // 4 gathers in flight
        unsigned int pb = xb2[sb * 64 + lane];
        unsigned int pc = xb2[sc * 64 + lane];
        unsigned int pd = xb2[sd * 64 + lane];
        float ma0 = fmaxf(lo_f(pa), 0.f), ma1 = fmaxf(hi_f(pa), 0.f);
        float mb0 = fmaxf(lo_f(pb), 0.f), mb1 = fmaxf(hi_f(pb), 0.f);
        float mc0 = fmaxf(lo_f(pc), 0.f), mc1 = fmaxf(hi_f(pc), 0.f);
        float md0 = fmaxf(lo_f(pd), 0.f), md1 = fmaxf(hi_f(pd), 0.f);
        float ea0 = exp2f(ma0 * tl), ea1 = exp2f(ma1 * tl);
        float eb0 = exp2f(mb0 * tl), eb1 = exp2f(mb1 * tl);
        float ec0 = exp2f(mc0 * tl), ec1 = exp2f(mc1 * tl);
        float ed0 = exp2f(md0 * tl), ed1 = exp2f(md1 * tl);
        s0  += ea0; m0  = fmaf(ea0, ma0, m0);
        s1  += ea1; m1  = fmaf(ea1, ma1, m1);
        s0b += eb0; m0b = fmaf(eb0, mb0, m0b);
        s1b += eb1; m1b = fmaf(eb1, mb1, m1b);
        s0  += ec0; m0  = fmaf(ec0, mc0, m0);
        s1  += ec1; m1  = fmaf(ec1, mc1, m1);
        s0b += ed0; m0b = fmaf(ed0, md0, m0b);
        s1b += ed1; m1b = fmaf(ed1, md1, m1b);
    }
    for (; j < end; ++j) {
        int sa = __builtin_amdgcn_readfirstlane(csr_src[j]);
        unsigned int pa = xb2[sa * 64 + lane];
        float ma0 = fmaxf(lo_f(pa), 0.f), ma1 = fmaxf(hi_f(pa), 0.f);
        float ea0 = exp2f(ma0 * tl), ea1 = exp2f(ma1 * tl);
        s0 += ea0; m0 = fmaf(ea0, ma0, m0);
        s1 += ea1; m1 = fmaf(ea1, ma1, m1);
    }
    float agg0 = (m0 + m0b) / (s0 + s0b + 1e-16f);
    float agg1 = (m1 + m1b) / (s1 + s1b + 1e-16f);
    unsigned int px = xb2[node * 64 + lane];          // bf16 residual
    h0b2[node * 64 + lane] = (unsigned int)f2b(agg0 + lo_f(px)) |
                             ((unsigned int)f2b(agg1 + hi_f(px)) << 16);
}

// ---------------- GEMM1 (MFMA): persistent B in registers, M-loop ----------------
__global__ __launch_bounds__(256) void gemm1_mfma(const unsigned short* __restrict__ h0b,
                                                  const unsigned short* __restrict__ W1t,
                                                  const float* __restrict__ b1,
                                                  unsigned short* __restrict__ h1b,
                                                  float* __restrict__ partial_s,
                                                  float* __restrict__ partial_ss) {
    __shared__ float red_s[4][256];
    __shared__ float red_ss[4][256];
    int tid = threadIdx.x;
    int wave = tid >> 6, lane = tid & 63;
    int quad = lane >> 4, m16 = lane & 15;
    int col0 = wave * 64;

    short8 bfr[4][4];    // [kk][f] resident weight fragments
    float bias[4];
#pragma unroll
    for (int f = 0; f < 4; ++f) {
        bias[f] = b1[col0 + f * 16 + m16];
#pragma unroll
        for (int kk = 0; kk < 4; ++kk)
            bfr[kk][f] = *(const short8*)(W1t + (col0 + f * 16 + m16) * D + kk * 32 + quad * 8);
    }
    float ps[4] = {0.f, 0.f, 0.f, 0.f}, pss[4] = {0.f, 0.f, 0.f, 0.f};

    for (int it = blockIdx.x; it < TILES; it += GRID_G) {
        int row0 = it * 16;
        const short8* aptr = (const short8*)(h0b + (row0 + m16) * D + quad * 8);
        short8 afr[4];
#pragma unroll
        for (int kk = 0; kk < 4; ++kk) afr[kk] = aptr[kk * 4];
        f32x4 acc[4];
#pragma unroll
        for (int f = 0; f < 4; ++f) acc[f] = (f32x4){0.f, 0.f, 0.f, 0.f};
#pragma unroll
        for (int kk = 0; kk < 4; ++kk)
#pragma unroll
            for (int f = 0; f < 4; ++f)
                acc[f] = __builtin_amdgcn_mfma_f32_16x16x32_bf16(afr[kk], bfr[kk][f], acc[f], 0, 0, 0);
#pragma unroll
        for (int f = 0; f < 4; ++f) {
            int col = col0 + f * 16 + m16;
#pragma unroll
            for (int r = 0; r < 4; ++r) {
                float v = acc[f][r] + bias[f];
                h1b[(row0 + quad * 4 + r) * TWO_D + col] = f2b(v);
                ps[f] += v;
                pss[f] += v * v;
            }
        }
    }
#pragma unroll
    for (int f = 0; f < 4; ++f) {
        float s = ps[f], ss = pss[f];
        s += __shfl_xor(s, 16);  s += __shfl_xor(s, 32);
        ss += __shfl_xor(ss, 16); ss += __shfl_xor(ss, 32);
        if (quad == 0) {
            red_s[wave][col0 + f * 16 + m16] = s;
            red_ss[wave][col0 + f * 16 + m16] = ss;
        }
    }
    __syncthreads();
    {
        int base = blockIdx.x * 256 + tid;
        partial_s[base]  = red_s[0][tid] + red_s[1][tid] + red_s[2][tid] + red_s[3][tid];
        partial_ss[base] = red_ss[0][tid] + red_ss[1][tid] + red_ss[2][tid] + red_ss[3][tid];
    }
}

// ---------------- BN reduce partials -> bnacc (low-contention atomics) ----------------
__global__ __launch_bounds__(256) void bn_reduce(const float* __restrict__ partial_s,
                                                 const float* __restrict__ partial_ss,
                                                 float* __restrict__ bnacc) {
    int c = threadIdx.x;
    float s = 0.f, ss = 0.f;
    for (int rb = blockIdx.x; rb < GRID_G; rb += 64) {
        s += partial_s[rb * 256 + c];
        ss += partial_ss[rb * 256 + c];
    }
    atomicAdd(&bnacc[c], s);
    atomicAdd(&bnacc[TWO_D + c], ss);
}

// ---------------- GEMM2 (MFMA): persistent B, M-loop; BN finalize + BN/ReLU stage + LN + mix ----------------
__global__ __launch_bounds__(256) void gemm2_mfma(const unsigned short* __restrict__ h1b,
                                                  const float* __restrict__ bnacc,
                                                  const float* __restrict__ bn_g,
                                                  const float* __restrict__ bn_b,
                                                  const unsigned short* __restrict__ W2t,
                                                  const float* __restrict__ b2,
                                                  const float* __restrict__ ln_g,
                                                  const float* __restrict__ ln_b,
                                                  const unsigned int* __restrict__ xb2,
                                                  float* __restrict__ out) {
    __shared__ float sc_s[TWO_D], sh_s[TWO_D];
    __shared__ unsigned short As[16][264];
    __shared__ float yt[16][132];
    __shared__ float mu_s[16], rstd_s[16];
    int tid = threadIdx.x;
    int wave = tid >> 6, lane = tid & 63;
    int quad = lane >> 4, m16 = lane & 15;

    {   // BN finalize per block (bnacc is 2KB, L2-resident)
        float mean = bnacc[tid] * (1.f / N_NODES);
        float var = bnacc[TWO_D + tid] * (1.f / N_NODES) - mean * mean;
        float sc = bn_g[tid] * rsqrtf(var + BN_EPS);
        sc_s[tid] = sc;
        sh_s[tid] = bn_b[tid] - mean * sc;
    }
    short8 bfr[8][2];    // resident W2t fragments
    float bias[2];
#pragma unroll
    for (int f = 0; f < 2; ++f) {
        int col = wave * 32 + f * 16 + m16;
        bias[f] = b2[col];
#pragma unroll
        for (int kk = 0; kk < 8; ++kk)
            bfr[kk][f] = *(const short8*)(W2t + col * TWO_D + kk * 32 + quad * 8);
    }
    int cp = tid & 63, rg = tid >> 6;
    float lg0 = ln_g[2 * cp], lg1 = ln_g[2 * cp + 1];
    float lb0 = ln_b[2 * cp], lb1 = ln_b[2 * cp + 1];
    int sr = tid >> 4, sc0 = (tid & 15) * 16;
    __syncthreads();

    for (int it = blockIdx.x; it < TILES; it += GRID_G) {
        int row0 = it * 16;
        {   // stage BN+ReLU'd A tile
            const unsigned short* srcp = h1b + (row0 + sr) * TWO_D + sc0;
            short8 v0 = *(const short8*)(srcp);
            short8 v1 = *(const short8*)(srcp + 8);
            short8 o0, o1;
#pragma unroll
            for (int jj = 0; jj < 8; ++jj) {
                float v = b2f((unsigned short)v0[jj]);
                v = fmaxf(v * sc_s[sc0 + jj] + sh_s[sc0 + jj], 0.f);
                o0[jj] = (short)f2b(v);
                float w = b2f((unsigned short)v1[jj]);
                w = fmaxf(w * sc_s[sc0 + 8 + jj] + sh_s[sc0 + 8 + jj], 0.f);
                o1[jj] = (short)f2b(w);
            }
            *(short8*)&As[sr][sc0] = o0;
            *(short8*)&As[sr][sc0 + 8] = o1;
        }
        __syncthreads();
        f32x4 acc[2] = {{0.f,0.f,0.f,0.f},{0.f,0.f,0.f,0.f}};
#pragma unroll
        for (int kk = 0; kk < 8; ++kk) {
            short8 a = *(const short8*)&As[m16][kk * 32 + quad * 8];
#pragma unroll
            for (int f = 0; f < 2; ++f)
                acc[f] = __builtin_amdgcn_mfma_f32_16x16x32_bf16(a, bfr[kk][f], acc[f], 0, 0, 0);
        }
#pragma unroll
        for (int f = 0; f < 2; ++f) {
            int col = wave * 32 + f * 16 + m16;
#pragma unroll
            for (int r = 0; r < 4; ++r) yt[quad * 4 + r][col] = acc[f][r] + bias[f];
        }
        __syncthreads();
        {   // LN stats: 16 threads per row
            int r = tid >> 4, lane16 = tid & 15;
            float s = 0.f, ss = 0.f;
            for (int jj = lane16; jj < D; jj += 16) {
                float v = yt[r][jj];
                s += v;
                ss += v * v;
            }
#pragma unroll
            for (int o = 1; o < 16; o <<= 1) {
                s += __shfl_xor(s, o);
                ss += __shfl_xor(ss, o);
            }
            if (lane16 == 0) {
                float mu = s * (1.f / D);
                float var = ss * (1.f / D) - mu * mu;
                mu_s[r] = mu;
                rstd_s[r] = rsqrtf(var + LN_EPS);
            }
        }
        __syncthreads();
#pragma unroll
        for (int rp = 0; rp < 4; ++rp) {
            int rl = rp * 4 + rg;
            int row = row0 + rl;
            unsigned int px = xb2[row * 64 + cp];
            float z0 = (yt[rl][2 * cp] - mu_s[rl]) * rstd_s[rl] * lg0 + lb0;
            float z1 = (yt[rl][2 * cp + 1] - mu_s[rl]) * rstd_s[rl] * lg1 + lb1;
            float o0 = 0.5f * lo_f(px) + 0.5f * fmaxf(z0, 0.f) + 0.5f * z0;
            float o1 = 0.5f * hi_f(px) + 0.5f * fmaxf(z1, 0.f) + 0.5f * z1;
            ((float2*)out)[row * 64 + cp] = make_float2(o0, o1);
        }
    }
}

// ---------------- launch ----------------

extern "C" void kernel_launch(void* const* d_in, const int* in_sizes, int n_in,
                              void* d_out, int out_size, void* d_ws, size_t ws_size,
                              hipStream_t stream) {
    const float* x    = (const float*)d_in[0];
    const int*   ei   = (const int*)d_in[1];
    const float* t    = (const float*)d_in[2];
    const float* W1   = (const float*)d_in[3];
    const float* b1   = (const float*)d_in[4];
    const float* bn_g = (const float*)d_in[5];
    const float* bn_b = (const float*)d_in[6];
    const float* W2   = (const float*)d_in[7];
    const float* b2   = (const float*)d_in[8];
    const float* ln_g = (const float*)d_in[9];
    const float* ln_b = (const float*)d_in[10];
    float* out = (float*)d_out;

    char* ws = (char*)d_ws;
    size_t off = 0;
    auto alloc = [&](size_t bytes) -> void* {
        void* p = ws + off;
        off = (off + bytes + 255) & ~(size_t)255;
        return p;
    };
    int*            counts     = (int*)alloc((size_t)N_NODES * 4);
    int*            offsets    = (int*)alloc((size_t)(N_NODES + 1) * 4);
    int*            rank       = (int*)alloc((size_t)N_EDGES * 4);
    int*            csr_src    = (int*)alloc((size_t)N_EDGES * 4);
    unsigned int*   xb2        = (unsigned int*)alloc((size_t)N_NODES * 64 * 4);
    unsigned int*   h0b2       = (unsigned int*)alloc((size_t)N_NODES * 64 * 4);
    unsigned short* h1b        = (unsigned short*)alloc((size_t)N_NODES * TWO_D * 2);
    unsigned short* W1t        = (unsigned short*)alloc((size_t)D * TWO_D * 2);
    unsigned short* W2t        = (unsigned short*)alloc((size_t)D * TWO_D * 2);
    float*          partial_s  = (float*)alloc((size_t)GRID_G * TWO_D * 4);
    float*          partial_ss = (float*)alloc((size_t)GRID_G * TWO_D * 4);
    float*          bnacc      = (float*)alloc(2 * TWO_D * 4);

    const int* src = ei;
    const int* dst = ei + N_EDGES;

    hipMemsetAsync(counts, 0, (size_t)N_NODES * 4, stream);
    prep_all<<<12500, 256, 0, stream>>>(x, W1, W2, dst, W1t, W2t, xb2, counts, rank, bnacc);
    scan_offsets<<<196, 256, 0, stream>>>(counts, offsets);
    scatter_kernel<<<(N_EDGES + 255) / 256, 256, 0, stream>>>(src, dst, offsets, rank, csr_src);
    agg_kernel<<<12500, 256, 0, stream>>>(xb2, offsets, csr_src, t, h0b2);
    gemm1_mfma<<<GRID_G, 256, 0, stream>>>((const unsigned short*)h0b2, W1t, b1, h1b,
                                           partial_s, partial_ss);
    bn_reduce<<<64, 256, 0, stream>>>(partial_s, partial_ss, bnacc);
    gemm2_mfma<<<GRID_G, 256, 0, stream>>>(h1b, bnacc, bn_g, bn_b, W2t, b2,
                                           ln_g, ln_b, xb2, out);
}